// Round 1
// baseline (1074.200 us; speedup 1.0000x reference)
//
#include <hip/hip_runtime.h>
#include <math.h>

#define BB   4
#define LL   4096
#define CCH  256
#define KK   7
#define HIDN 32
#define MTOT (BB * LL)          // 16384 rows
#define NOFF (CCH * KK)         // 1792

__device__ __forceinline__ float siluf(float v) { return v / (1.0f + expf(-v)); }

// ---------------- precompute: env, kernel-net MLP, zero accumulators ----------------
__global__ __launch_bounds__(256) void precompute_kernel(
    const float* __restrict__ raw_sigma,
    const float* __restrict__ k0w, const float* __restrict__ k0b,
    const float* __restrict__ k1w, const float* __restrict__ k1b,
    const float* __restrict__ k2w, const float* __restrict__ k2b,
    const float* __restrict__ k3w, const float* __restrict__ k3b,
    float* __restrict__ kwf, float* __restrict__ env, float* __restrict__ accum)
{
    __shared__ float h0[KK][HIDN];
    __shared__ float h1[KK][HIDN];
    __shared__ float h2[KK][HIDN];
    int t = threadIdx.x;
    if (t < 2) accum[t] = 0.0f;
    if (t < KK * HIDN) {
        int k = t / HIDN, j = t % HIDN;
        float gk = -0.5f + (float)k * (1.0f / 6.0f);
        float v = gk * 30.0f * k0w[j] + k0b[j];
        h0[k][j] = siluf(v);
    }
    __syncthreads();
    if (t < KK * HIDN) {
        int k = t / HIDN, j = t % HIDN;
        float s = k1b[j];
        #pragma unroll
        for (int i = 0; i < HIDN; ++i) s += h0[k][i] * k1w[i * HIDN + j];
        h1[k][j] = siluf(s);
    }
    __syncthreads();
    if (t < KK * HIDN) {
        int k = t / HIDN, j = t % HIDN;
        float s = k2b[j];
        #pragma unroll
        for (int i = 0; i < HIDN; ++i) s += h1[k][i] * k2w[i * HIDN + j];
        h2[k][j] = siluf(s);
    }
    __syncthreads();
    // output layer: kernel_weights[k][n], n = t
    for (int k = 0; k < KK; ++k) {
        float s = k3b[t];
        #pragma unroll
        for (int i = 0; i < HIDN; ++i) s += h2[k][i] * k3w[i * CCH + t];
        kwf[k * CCH + t] = s;   // flat layout; sampler indexes flat[g*7+k] (raw reshape)
    }
    if (t == 0) {
        float sp = log1pf(expf(raw_sigma[0]));      // softplus
        sp = fminf(fmaxf(sp, 0.05f), 0.5f);         // clip to [MIN_SIGMA, MAX_SIGMA]
        float sg = fmaxf(sp, 1e-6f);
        float ev[KK]; float ssum = 0.0f;
        for (int k = 0; k < KK; ++k) {
            float gk = -0.5f + (float)k * (1.0f / 6.0f);
            float d = gk / sg;
            ev[k] = expf(-0.5f * d * d);
            ssum += ev[k];
        }
        ssum = fmaxf(ssum, 1e-8f);
        for (int k = 0; k < KK; ++k) env[k] = ev[k] / ssum;
    }
}

// ---------------- generic fp32 GEMM: C[M,N] = A[M,K] @ W[K,N] + bias ----------------
// BM=64, BN=64, BK=16, 256 threads, 4x4 per thread. M%64==0, N%64==0, K%16==0.
__global__ __launch_bounds__(256) void gemm_bias_f32(
    const float* __restrict__ A, const float* __restrict__ W,
    const float* __restrict__ bias, float* __restrict__ C,
    int M, int N, int Kd)
{
    __shared__ float As[64][17];   // [m][k], +1 pad breaks read conflicts
    __shared__ float Ws[16][64];   // [k][n]
    const int tid = threadIdx.x;
    const int tr = tid >> 4;       // 0..15
    const int tc = tid & 15;       // 0..15
    const int m0 = blockIdx.y * 64;
    const int n0 = blockIdx.x * 64;

    const int la_m = tid >> 2;           // 0..63
    const int la_k = (tid & 3) * 4;      // 0,4,8,12
    const int lw_k = tid >> 4;           // 0..15
    const int lw_n = (tid & 15) * 4;     // 0..60

    float acc[4][4] = {};

    for (int k0 = 0; k0 < Kd; k0 += 16) {
        float4 av = *(const float4*)&A[(size_t)(m0 + la_m) * Kd + k0 + la_k];
        As[la_m][la_k + 0] = av.x;
        As[la_m][la_k + 1] = av.y;
        As[la_m][la_k + 2] = av.z;
        As[la_m][la_k + 3] = av.w;
        float4 wv = *(const float4*)&W[(size_t)(k0 + lw_k) * N + n0 + lw_n];
        *(float4*)&Ws[lw_k][lw_n] = wv;
        __syncthreads();
        #pragma unroll
        for (int kk = 0; kk < 16; ++kk) {
            float a0 = As[tr * 4 + 0][kk];
            float a1 = As[tr * 4 + 1][kk];
            float a2 = As[tr * 4 + 2][kk];
            float a3 = As[tr * 4 + 3][kk];
            float4 b4 = *(const float4*)&Ws[kk][tc * 4];
            acc[0][0] += a0 * b4.x; acc[0][1] += a0 * b4.y; acc[0][2] += a0 * b4.z; acc[0][3] += a0 * b4.w;
            acc[1][0] += a1 * b4.x; acc[1][1] += a1 * b4.y; acc[1][2] += a1 * b4.z; acc[1][3] += a1 * b4.w;
            acc[2][0] += a2 * b4.x; acc[2][1] += a2 * b4.y; acc[2][2] += a2 * b4.z; acc[2][3] += a2 * b4.w;
            acc[3][0] += a3 * b4.x; acc[3][1] += a3 * b4.y; acc[3][2] += a3 * b4.z; acc[3][3] += a3 * b4.w;
        }
        __syncthreads();
    }
    float4 bb = *(const float4*)&bias[n0 + tc * 4];
    #pragma unroll
    for (int i = 0; i < 4; ++i) {
        float4 o;
        o.x = acc[i][0] + bb.x;
        o.y = acc[i][1] + bb.y;
        o.z = acc[i][2] + bb.z;
        o.w = acc[i][3] + bb.w;
        *(float4*)&C[(size_t)(m0 + tr * 4 + i) * N + n0 + tc * 4] = o;
    }
}

// ---------------- depthwise conv3 + bias + SiLU ----------------
__global__ __launch_bounds__(256) void dwconv_silu_kernel(
    const float* __restrict__ x, const float* __restrict__ w1,
    const float* __restrict__ b1, float* __restrict__ h)
{
    size_t idx = (size_t)blockIdx.x * 256 + threadIdx.x;   // over B*L*C
    int c = (int)(idx & (CCH - 1));
    int l = (int)((idx >> 8) & (LL - 1));
    float s = x[idx] * w1[c * 3 + 1];
    if (l > 0)      s += x[idx - CCH] * w1[c * 3 + 0];
    if (l < LL - 1) s += x[idx + CCH] * w1[c * 3 + 2];
    s += b1[c];
    h[idx] = siluf(s);
}

// ---------------- sampling + softmax + weighted sum + reductions ----------------
__global__ __launch_bounds__(256) void sample_kernel(
    const float* __restrict__ xproj, const float* __restrict__ off_raw,
    const float* __restrict__ mask_raw, const float* __restrict__ kwf,
    const float* __restrict__ env, float* __restrict__ out_pre,
    float* __restrict__ accum, int chunk_start)
{
    const int r = blockIdx.x;
    const int R = chunk_start + r;
    const int b = R >> 12;           // L = 4096
    const int l = R & (LL - 1);
    const int g = threadIdx.x;

    const float* offp = off_raw + (size_t)r * NOFF + g * KK;
    const float* mp   = mask_raw + (size_t)r * NOFF + g * KK;
    const float* xb   = xproj + (size_t)b * LL * CCH + g;

    float envr[KK];
    #pragma unroll
    for (int k = 0; k < KK; ++k) envr[k] = env[k];

    float reg_part = 0.0f;
    float sampk[KK], mv[KK];
    #pragma unroll
    for (int k = 0; k < KK; ++k) {
        float ov = tanhf(offp[k]) * 2.0f;
        reg_part += ov * ov;
        float p = (float)(l + k - 3) + ov;
        p = fminf(fmaxf(p, 0.0f), (float)(LL - 1));
        int pf = (int)p;
        int pc = min(pf + 1, LL - 1);
        float wc = p - (float)pf;
        float sv = xb[(size_t)pf * CCH] * (1.0f - wc) + xb[(size_t)pc * CCH] * wc;
        sampk[k] = sv * kwf[g * KK + k];
        mv[k] = mp[k] * envr[k];
    }
    float mx = mv[0];
    #pragma unroll
    for (int k = 1; k < KK; ++k) mx = fmaxf(mx, mv[k]);
    float e[KK], es = 0.0f;
    #pragma unroll
    for (int k = 0; k < KK; ++k) { e[k] = expf(mv[k] - mx); es += e[k]; }
    float inv = 1.0f / es;
    float o = 0.0f, ent = 0.0f;
    #pragma unroll
    for (int k = 0; k < KK; ++k) {
        float a = e[k] * inv;
        o += sampk[k] * a;
        ent += a * logf(a + 1e-8f);
    }
    out_pre[(size_t)R * CCH + g] = o;

    __shared__ float red[256];
    red[g] = reg_part;
    __syncthreads();
    for (int s = 128; s > 0; s >>= 1) { if (g < s) red[g] += red[g + s]; __syncthreads(); }
    if (g == 0) atomicAdd(&accum[0], red[0]);
    __syncthreads();
    red[g] = ent;
    __syncthreads();
    for (int s = 128; s > 0; s >>= 1) { if (g < s) red[g] += red[g + s]; __syncthreads(); }
    if (g == 0) atomicAdd(&accum[1], red[0]);
}

// ---------------- finalize scalars ----------------
__global__ void finalize_kernel(const float* __restrict__ accum, float* __restrict__ out_tail)
{
    if (threadIdx.x == 0) {
        out_tail[0] = accum[0] / 29360128.0f;   // B*L*G*K
        out_tail[1] = accum[1] / 4194304.0f;    // B*L*G  (this is -entropy)
    }
}

extern "C" void kernel_launch(void* const* d_in, const int* in_sizes, int n_in,
                              void* d_out, int out_size, void* d_ws, size_t ws_size,
                              hipStream_t stream)
{
    const float* x         = (const float*)d_in[0];
    const float* raw_sigma = (const float*)d_in[1];
    const float* w_in      = (const float*)d_in[2];
    const float* b_in      = (const float*)d_in[3];
    const float* w_out     = (const float*)d_in[4];
    const float* b_out     = (const float*)d_in[5];
    const float* dw1_w     = (const float*)d_in[6];
    const float* dw1_b     = (const float*)d_in[7];
    const float* dw2_w     = (const float*)d_in[8];
    const float* dw2_b     = (const float*)d_in[9];
    const float* w_off     = (const float*)d_in[10];
    const float* b_off     = (const float*)d_in[11];
    const float* w_mask    = (const float*)d_in[12];
    const float* b_mask    = (const float*)d_in[13];
    const float* k0w       = (const float*)d_in[14];
    const float* k0b       = (const float*)d_in[15];
    const float* k1w       = (const float*)d_in[16];
    const float* k1b       = (const float*)d_in[17];
    const float* k2w       = (const float*)d_in[18];
    const float* k2b       = (const float*)d_in[19];
    const float* k3w       = (const float*)d_in[20];
    const float* k3b       = (const float*)d_in[21];

    char* ws = (char*)d_ws;
    const size_t SZ16 = (size_t)16 * 1024 * 1024;     // 16 MB = MTOT*CCH*4
    float* xproj = (float*)(ws + 0);
    float* hbuf  = (float*)(ws + SZ16);               // h, later reused as out_pre
    float* xdw   = (float*)(ws + 2 * SZ16);
    float* smallbuf = (float*)(ws + 3 * SZ16);
    float* kwf   = smallbuf;                          // 1792 floats
    float* env   = smallbuf + 2048;                   // 7 floats
    float* accum = smallbuf + 2048 + 16;              // 2 floats
    const size_t fixed = 3 * SZ16 + 65536;

    // adaptive chunking of off/mask intermediates
    int CH = MTOT;   // 16384
    while (CH > 256) {
        size_t need = fixed + (size_t)CH * NOFF * 4 * 2;
        if (need <= ws_size) break;
        CH >>= 1;
    }
    float* offc  = (float*)(ws + fixed);
    float* maskc = offc + (size_t)CH * NOFF;

    // 1) precompute env / kernel weights / zero accumulators
    precompute_kernel<<<1, 256, 0, stream>>>(raw_sigma, k0w, k0b, k1w, k1b,
                                             k2w, k2b, k3w, k3b, kwf, env, accum);
    // 2) x_proj = x @ w_in + b_in
    gemm_bias_f32<<<dim3(CCH / 64, MTOT / 64), 256, 0, stream>>>(x, w_in, b_in, xproj, MTOT, CCH, CCH);
    // 3) h = silu(dwconv3(x) + dw1_b)
    dwconv_silu_kernel<<<(MTOT * CCH) / 256, 256, 0, stream>>>(x, dw1_w, dw1_b, hbuf);
    // 4) x_dw = h @ dw2_w + dw2_b
    gemm_bias_f32<<<dim3(CCH / 64, MTOT / 64), 256, 0, stream>>>(hbuf, dw2_w, dw2_b, xdw, MTOT, CCH, CCH);
    // 5) chunked: offsets GEMM, mask GEMM, fused sampling (writes out_pre into hbuf)
    for (int c0 = 0; c0 < MTOT; c0 += CH) {
        gemm_bias_f32<<<dim3(NOFF / 64, CH / 64), 256, 0, stream>>>(
            xdw + (size_t)c0 * CCH, w_off, b_off, offc, CH, NOFF, CCH);
        gemm_bias_f32<<<dim3(NOFF / 64, CH / 64), 256, 0, stream>>>(
            xdw + (size_t)c0 * CCH, w_mask, b_mask, maskc, CH, NOFF, CCH);
        sample_kernel<<<CH, 256, 0, stream>>>(xproj, offc, maskc, kwf, env, hbuf, accum, c0);
    }
    // 6) out = out_pre @ w_out + b_out
    gemm_bias_f32<<<dim3(CCH / 64, MTOT / 64), 256, 0, stream>>>(
        hbuf, w_out, b_out, (float*)d_out, MTOT, CCH, CCH);
    // 7) scalars
    finalize_kernel<<<1, 64, 0, stream>>>(accum, (float*)d_out + (size_t)MTOT * CCH);
}

// Round 2
// 569.962 us; speedup vs baseline: 1.8847x; 1.8847x over previous
//
#include <hip/hip_runtime.h>
#include <hip/hip_bf16.h>
#include <math.h>

#define BB   4
#define LL   4096
#define CCH  256
#define KK   7
#define HIDN 32
#define MTOT (BB * LL)          // 16384 rows
#define NOFF (CCH * KK)         // 1792

typedef __attribute__((ext_vector_type(8))) short short8;
typedef __attribute__((ext_vector_type(4))) float f32x4;
typedef __attribute__((address_space(1))) void gvoid_t;
typedef __attribute__((address_space(3))) void svoid_t;

__device__ __forceinline__ float siluf(float v) { return v / (1.0f + expf(-v)); }

// ---------------- precompute: env, kernel-net MLP, zero accumulators ----------------
__global__ __launch_bounds__(256) void precompute_kernel(
    const float* __restrict__ raw_sigma,
    const float* __restrict__ k0w, const float* __restrict__ k0b,
    const float* __restrict__ k1w, const float* __restrict__ k1b,
    const float* __restrict__ k2w, const float* __restrict__ k2b,
    const float* __restrict__ k3w, const float* __restrict__ k3b,
    float* __restrict__ kwf, float* __restrict__ env, float* __restrict__ accum)
{
    __shared__ float h0[KK][HIDN];
    __shared__ float h1[KK][HIDN];
    __shared__ float h2[KK][HIDN];
    int t = threadIdx.x;
    if (t < 2) accum[t] = 0.0f;
    if (t < KK * HIDN) {
        int k = t / HIDN, j = t % HIDN;
        float gk = -0.5f + (float)k * (1.0f / 6.0f);
        float v = gk * 30.0f * k0w[j] + k0b[j];
        h0[k][j] = siluf(v);
    }
    __syncthreads();
    if (t < KK * HIDN) {
        int k = t / HIDN, j = t % HIDN;
        float s = k1b[j];
        #pragma unroll
        for (int i = 0; i < HIDN; ++i) s += h0[k][i] * k1w[i * HIDN + j];
        h1[k][j] = siluf(s);
    }
    __syncthreads();
    if (t < KK * HIDN) {
        int k = t / HIDN, j = t % HIDN;
        float s = k2b[j];
        #pragma unroll
        for (int i = 0; i < HIDN; ++i) s += h1[k][i] * k2w[i * HIDN + j];
        h2[k][j] = siluf(s);
    }
    __syncthreads();
    for (int k = 0; k < KK; ++k) {
        float s = k3b[t];
        #pragma unroll
        for (int i = 0; i < HIDN; ++i) s += h2[k][i] * k3w[i * CCH + t];
        kwf[k * CCH + t] = s;   // flat layout; sampler indexes flat[g*7+k] (raw reshape)
    }
    if (t == 0) {
        float sp = log1pf(expf(raw_sigma[0]));
        sp = fminf(fmaxf(sp, 0.05f), 0.5f);
        float sg = fmaxf(sp, 1e-6f);
        float ev[KK]; float ssum = 0.0f;
        for (int k = 0; k < KK; ++k) {
            float gk = -0.5f + (float)k * (1.0f / 6.0f);
            float d = gk / sg;
            ev[k] = expf(-0.5f * d * d);
            ssum += ev[k];
        }
        ssum = fmaxf(ssum, 1e-8f);
        for (int k = 0; k < KK; ++k) env[k] = ev[k] / ssum;
    }
}

// ---------------- prep: x -> bf16; weights [K=256][N] fp32 -> [N][K=256] bf16 ----------------
__global__ __launch_bounds__(256) void prep_kernel(
    const float* __restrict__ x,
    const float* __restrict__ w_in, const float* __restrict__ dw2_w,
    const float* __restrict__ w_out, const float* __restrict__ w_off,
    const float* __restrict__ w_mask,
    __hip_bfloat16* __restrict__ xbf,
    __hip_bfloat16* __restrict__ wtin, __hip_bfloat16* __restrict__ wtdw2,
    __hip_bfloat16* __restrict__ wtout, __hip_bfloat16* __restrict__ wtoff,
    __hip_bfloat16* __restrict__ wtmask)
{
    const int task = blockIdx.y;
    const int tid = threadIdx.x;
    if (task == 0) {
        size_t base = ((size_t)blockIdx.x * 256 + tid) * 4;   // grid.x=4096 covers exactly
        float4 v = *(const float4*)&x[base];
        xbf[base + 0] = __float2bfloat16(v.x);
        xbf[base + 1] = __float2bfloat16(v.y);
        xbf[base + 2] = __float2bfloat16(v.z);
        xbf[base + 3] = __float2bfloat16(v.w);
        return;
    }
    const float* src; __hip_bfloat16* dst; int N;
    switch (task) {
        case 1: src = w_in;  dst = wtin;  N = 256;  break;
        case 2: src = dw2_w; dst = wtdw2; N = 256;  break;
        case 3: src = w_out; dst = wtout; N = 256;  break;
        case 4: src = w_off; dst = wtoff; N = 1792; break;
        default: src = w_mask; dst = wtmask; N = 1792; break;
    }
    int ntiles = 4 * (N / 64);
    if (blockIdx.x >= (unsigned)ntiles) return;
    int tk = (blockIdx.x & 3) * 64;
    int tn = (blockIdx.x >> 2) * 64;
    __shared__ __hip_bfloat16 t[64][66];
    #pragma unroll
    for (int i = 0; i < 16; ++i) {
        int e = i * 256 + tid, kk = e >> 6, nn = e & 63;
        t[kk][nn] = __float2bfloat16(src[(size_t)(tk + kk) * N + tn + nn]);
    }
    __syncthreads();
    #pragma unroll
    for (int i = 0; i < 16; ++i) {
        int e = i * 256 + tid, nn = e >> 6, kk = e & 63;
        dst[(size_t)(tn + nn) * 256 + tk + kk] = t[kk][nn];
    }
}

// ---------------- depthwise conv3 + bias + SiLU -> bf16 ----------------
__global__ __launch_bounds__(256) void dwconv_silu_kernel(
    const float* __restrict__ x, const float* __restrict__ w1,
    const float* __restrict__ b1, __hip_bfloat16* __restrict__ h)
{
    size_t idx = (size_t)blockIdx.x * 256 + threadIdx.x;   // over B*L*C
    int c = (int)(idx & (CCH - 1));
    int l = (int)((idx >> 8) & (LL - 1));
    float s = x[idx] * w1[c * 3 + 1];
    if (l > 0)      s += x[idx - CCH] * w1[c * 3 + 0];
    if (l < LL - 1) s += x[idx + CCH] * w1[c * 3 + 2];
    s += b1[c];
    h[idx] = __float2bfloat16(siluf(s));
}

// ---------------- bf16 MFMA GEMM: C[rows][N] = A[rows][256] @ Bt[N][256]^T + bias ----------------
// 128x128 tile, 4 waves (2x2, 64x64 each), BK=64, global_load_lds w/ pre-swizzled src.
template<int OUTBF>
__global__ __launch_bounds__(256) void gemm_bf16_k256(
    const __hip_bfloat16* __restrict__ A,
    const __hip_bfloat16* __restrict__ Bt,
    const float* __restrict__ bias,
    void* __restrict__ C, int N)
{
    __shared__ __align__(16) char lds[32768];
    char* As = lds;
    char* Bs = lds + 16384;
    const int tid = threadIdx.x, lane = tid & 63, w = tid >> 6;
    const int wr = w >> 1, wc = w & 1;
    const size_t m0 = (size_t)blockIdx.y * 128, n0 = (size_t)blockIdx.x * 128;

    // staging: each wave stages 32 rows of A and of B (4 insts x 8 rows, 16B/lane)
    const int srow = w * 32 + (lane >> 3);
    const int sgr  = (lane & 7) ^ ((lane >> 3) & 7);        // swizzled source granule
    const __hip_bfloat16* a_src = A  + (m0 + srow) * 256 + sgr * 8;
    const __hip_bfloat16* b_src = Bt + (n0 + srow) * 256 + sgr * 8;
    char* a_dst = As + (w * 32) * 128;
    char* b_dst = Bs + (w * 32) * 128;

    f32x4 acc[4][4] = {};

    for (int kt = 0; kt < 4; ++kt) {
        const int k0 = kt * 64;
        #pragma unroll
        for (int inst = 0; inst < 4; ++inst) {
            __builtin_amdgcn_global_load_lds((gvoid_t*)(a_src + k0 + (size_t)inst * 8 * 256),
                                             (svoid_t*)(a_dst + inst * 1024), 16, 0, 0);
            __builtin_amdgcn_global_load_lds((gvoid_t*)(b_src + k0 + (size_t)inst * 8 * 256),
                                             (svoid_t*)(b_dst + inst * 1024), 16, 0, 0);
        }
        __syncthreads();
        #pragma unroll
        for (int ks = 0; ks < 2; ++ks) {
            short8 a[4], b[4];
            #pragma unroll
            for (int i = 0; i < 4; ++i) {
                int mr = wr * 64 + i * 16 + (lane & 15);
                int gk = ks * 4 + (lane >> 4);
                a[i] = *(const short8*)(As + mr * 128 + ((gk ^ (mr & 7)) << 4));
                int nr = wc * 64 + i * 16 + (lane & 15);
                b[i] = *(const short8*)(Bs + nr * 128 + ((gk ^ (nr & 7)) << 4));
            }
            #pragma unroll
            for (int i = 0; i < 4; ++i)
                #pragma unroll
                for (int j = 0; j < 4; ++j)
                    acc[i][j] = __builtin_amdgcn_mfma_f32_16x16x32_bf16(a[i], b[j], acc[i][j], 0, 0, 0);
        }
        __syncthreads();
    }
    // epilogue: C/D layout col=lane&15, row=(lane>>4)*4+q  [measured m89/m91]
    #pragma unroll
    for (int j = 0; j < 4; ++j) {
        int col = (int)n0 + wc * 64 + j * 16 + (lane & 15);
        float bb = bias[col];
        #pragma unroll
        for (int i = 0; i < 4; ++i) {
            size_t row0 = m0 + wr * 64 + i * 16 + ((lane >> 4) << 2);
            f32x4 v = acc[i][j];
            #pragma unroll
            for (int q = 0; q < 4; ++q) {
                float val = v[q] + bb;
                if (OUTBF) ((__hip_bfloat16*)C)[(row0 + q) * N + col] = __float2bfloat16(val);
                else       ((float*)C)[(row0 + q) * N + col] = val;
            }
        }
    }
}

// ---------------- sampling + softmax + weighted sum + reductions ----------------
__global__ __launch_bounds__(256) void sample_kernel(
    const __hip_bfloat16* __restrict__ xproj,
    const __hip_bfloat16* __restrict__ off_raw,
    const __hip_bfloat16* __restrict__ mask_raw,
    const float* __restrict__ kwf, const float* __restrict__ env,
    __hip_bfloat16* __restrict__ out_pre, float* __restrict__ accum, int chunk_start)
{
    const int r = blockIdx.x;
    const int R = chunk_start + r;
    const int b = R >> 12;           // L = 4096
    const int l = R & (LL - 1);
    const int g = threadIdx.x;

    const __hip_bfloat16* offp = off_raw + (size_t)r * NOFF + g * KK;
    const __hip_bfloat16* mp   = mask_raw + (size_t)r * NOFF + g * KK;
    const __hip_bfloat16* xb   = xproj + (size_t)b * LL * CCH + g;

    float envr[KK];
    #pragma unroll
    for (int k = 0; k < KK; ++k) envr[k] = env[k];

    float reg_part = 0.0f;
    float sampk[KK], mv[KK];
    #pragma unroll
    for (int k = 0; k < KK; ++k) {
        float ov = tanhf(__bfloat162float(offp[k])) * 2.0f;
        reg_part += ov * ov;
        float p = (float)(l + k - 3) + ov;
        p = fminf(fmaxf(p, 0.0f), (float)(LL - 1));
        int pf = (int)p;
        int pc = min(pf + 1, LL - 1);
        float wcf = p - (float)pf;
        float sv = __bfloat162float(xb[(size_t)pf * CCH]) * (1.0f - wcf)
                 + __bfloat162float(xb[(size_t)pc * CCH]) * wcf;
        sampk[k] = sv * kwf[g * KK + k];
        mv[k] = __bfloat162float(mp[k]) * envr[k];
    }
    float mx = mv[0];
    #pragma unroll
    for (int k = 1; k < KK; ++k) mx = fmaxf(mx, mv[k]);
    float e[KK], es = 0.0f;
    #pragma unroll
    for (int k = 0; k < KK; ++k) { e[k] = expf(mv[k] - mx); es += e[k]; }
    float inv = 1.0f / es;
    float o = 0.0f, ent = 0.0f;
    #pragma unroll
    for (int k = 0; k < KK; ++k) {
        float a = e[k] * inv;
        o += sampk[k] * a;
        ent += a * logf(a + 1e-8f);
    }
    out_pre[(size_t)R * CCH + g] = __float2bfloat16(o);

    __shared__ float red[256];
    red[g] = reg_part;
    __syncthreads();
    for (int s = 128; s > 0; s >>= 1) { if (g < s) red[g] += red[g + s]; __syncthreads(); }
    if (g == 0) atomicAdd(&accum[0], red[0]);
    __syncthreads();
    red[g] = ent;
    __syncthreads();
    for (int s = 128; s > 0; s >>= 1) { if (g < s) red[g] += red[g + s]; __syncthreads(); }
    if (g == 0) atomicAdd(&accum[1], red[0]);
}

// ---------------- finalize scalars ----------------
__global__ void finalize_kernel(const float* __restrict__ accum, float* __restrict__ out_tail)
{
    if (threadIdx.x == 0) {
        out_tail[0] = accum[0] / 29360128.0f;   // B*L*G*K
        out_tail[1] = accum[1] / 4194304.0f;    // B*L*G
    }
}

extern "C" void kernel_launch(void* const* d_in, const int* in_sizes, int n_in,
                              void* d_out, int out_size, void* d_ws, size_t ws_size,
                              hipStream_t stream)
{
    const float* x         = (const float*)d_in[0];
    const float* raw_sigma = (const float*)d_in[1];
    const float* w_in      = (const float*)d_in[2];
    const float* b_in      = (const float*)d_in[3];
    const float* w_out     = (const float*)d_in[4];
    const float* b_out     = (const float*)d_in[5];
    const float* dw1_w     = (const float*)d_in[6];
    const float* dw1_b     = (const float*)d_in[7];
    const float* dw2_w     = (const float*)d_in[8];
    const float* dw2_b     = (const float*)d_in[9];
    const float* w_off     = (const float*)d_in[10];
    const float* b_off     = (const float*)d_in[11];
    const float* w_mask    = (const float*)d_in[12];
    const float* b_mask    = (const float*)d_in[13];
    const float* k0w       = (const float*)d_in[14];
    const float* k0b       = (const float*)d_in[15];
    const float* k1w       = (const float*)d_in[16];
    const float* k1b       = (const float*)d_in[17];
    const float* k2w       = (const float*)d_in[18];
    const float* k2b       = (const float*)d_in[19];
    const float* k3w       = (const float*)d_in[20];
    const float* k3b       = (const float*)d_in[21];

    char* ws = (char*)d_ws;
    const size_t MB8 = (size_t)8 * 1024 * 1024;
    __hip_bfloat16* xbf    = (__hip_bfloat16*)(ws + 0);
    __hip_bfloat16* hbf    = (__hip_bfloat16*)(ws + MB8);        // h, reused as out_pre
    __hip_bfloat16* xdwbf  = (__hip_bfloat16*)(ws + 2 * MB8);
    __hip_bfloat16* xprojb = (__hip_bfloat16*)(ws + 3 * MB8);
    char* wbase = ws + 4 * MB8;
    __hip_bfloat16* wtin   = (__hip_bfloat16*)(wbase);
    __hip_bfloat16* wtdw2  = (__hip_bfloat16*)(wbase + 131072);
    __hip_bfloat16* wtout  = (__hip_bfloat16*)(wbase + 262144);
    __hip_bfloat16* wtoff  = (__hip_bfloat16*)(wbase + 393216);
    __hip_bfloat16* wtmask = (__hip_bfloat16*)(wbase + 393216 + 917504);
    float* kwf   = (float*)(wbase + 2228224);
    float* env   = kwf + 2048;
    float* accum = env + 16;
    const size_t fixed = 4 * MB8 + 2228224 + 16384;   // 256-aligned

    // adaptive chunking of off/mask bf16 intermediates
    int CH = MTOT;   // 16384
    while (CH > 128) {
        size_t need = fixed + (size_t)CH * NOFF * 2 * 2;
        if (need <= ws_size) break;
        CH >>= 1;
    }
    __hip_bfloat16* offc  = (__hip_bfloat16*)(ws + fixed);
    __hip_bfloat16* maskc = offc + (size_t)CH * NOFF;

    // 1) env / kernel weights / zero accumulators
    precompute_kernel<<<1, 256, 0, stream>>>(raw_sigma, k0w, k0b, k1w, k1b,
                                             k2w, k2b, k3w, k3b, kwf, env, accum);
    // 2) conversions + weight transposes
    prep_kernel<<<dim3(4096, 6), 256, 0, stream>>>(x, w_in, dw2_w, w_out, w_off, w_mask,
                                                   xbf, wtin, wtdw2, wtout, wtoff, wtmask);
    // 3) h = silu(dwconv3(x) + dw1_b)  (bf16)
    dwconv_silu_kernel<<<(MTOT * CCH) / 256, 256, 0, stream>>>(x, dw1_w, dw1_b, hbf);
    // 4) x_proj = x @ w_in + b_in   (bf16 out)
    gemm_bf16_k256<1><<<dim3(2, 128), 256, 0, stream>>>(xbf, wtin, b_in, xprojb, 256);
    // 5) x_dw = h @ dw2_w + dw2_b   (bf16 out)
    gemm_bf16_k256<1><<<dim3(2, 128), 256, 0, stream>>>(hbf, wtdw2, dw2_b, xdwbf, 256);
    // 6) chunked: offsets GEMM, mask GEMM, fused sampling (out_pre -> hbf)
    for (int c0 = 0; c0 < MTOT; c0 += CH) {
        gemm_bf16_k256<1><<<dim3(14, CH / 128), 256, 0, stream>>>(
            xdwbf + (size_t)c0 * 256, wtoff, b_off, offc, NOFF);
        gemm_bf16_k256<1><<<dim3(14, CH / 128), 256, 0, stream>>>(
            xdwbf + (size_t)c0 * 256, wtmask, b_mask, maskc, NOFF);
        sample_kernel<<<CH, 256, 0, stream>>>(xprojb, offc, maskc, kwf, env, hbf, accum, c0);
    }
    // 7) out = out_pre @ w_out + b_out  (fp32 out)
    gemm_bf16_k256<0><<<dim3(2, 128), 256, 0, stream>>>(hbf, wtout, b_out, (float*)d_out, 256);
    // 8) scalars
    finalize_kernel<<<1, 64, 0, stream>>>(accum, (float*)d_out + (size_t)MTOT * CCH);
}

// Round 3
// 201.154 us; speedup vs baseline: 5.3402x; 2.8335x over previous
//
#include <hip/hip_runtime.h>
#include <hip/hip_bf16.h>
#include <math.h>

#define BB   4
#define LL   4096
#define CCH  256
#define KK   7
#define HIDN 32
#define MTOT (BB * LL)          // 16384 rows
#define NOFF (CCH * KK)         // 1792
#define NCOMB (2 * NOFF)        // 3584 (off planes | mask planes)
#define ROWS 8                  // rows per sample block

typedef __attribute__((ext_vector_type(8))) short short8;
typedef __attribute__((ext_vector_type(4))) float f32x4;
typedef __attribute__((address_space(1))) void gvoid_t;
typedef __attribute__((address_space(3))) void svoid_t;

__device__ __forceinline__ float siluf(float v) { return v / (1.0f + expf(-v)); }

// ---------------- precompute: env, kernel-net MLP (permuted), biases, accumulators ----------------
__global__ __launch_bounds__(256) void precompute_kernel(
    const float* __restrict__ raw_sigma,
    const float* __restrict__ k0w, const float* __restrict__ k0b,
    const float* __restrict__ k1w, const float* __restrict__ k1b,
    const float* __restrict__ k2w, const float* __restrict__ k2b,
    const float* __restrict__ k3w, const float* __restrict__ k3b,
    const float* __restrict__ b_off, const float* __restrict__ b_mask,
    float* __restrict__ kwp, float* __restrict__ bcomb,
    float* __restrict__ env, float* __restrict__ accum)
{
    __shared__ float h0[KK][HIDN];
    __shared__ float h1[KK][HIDN];
    __shared__ float h2[KK][HIDN];
    __shared__ float flatw[NOFF];
    int t = threadIdx.x;
    if (t < 2) accum[t] = 0.0f;
    if (t < KK * HIDN) {
        int k = t / HIDN, j = t % HIDN;
        float gk = -0.5f + (float)k * (1.0f / 6.0f);
        float v = gk * 30.0f * k0w[j] + k0b[j];
        h0[k][j] = siluf(v);
    }
    __syncthreads();
    if (t < KK * HIDN) {
        int k = t / HIDN, j = t % HIDN;
        float s = k1b[j];
        #pragma unroll
        for (int i = 0; i < HIDN; ++i) s += h0[k][i] * k1w[i * HIDN + j];
        h1[k][j] = siluf(s);
    }
    __syncthreads();
    if (t < KK * HIDN) {
        int k = t / HIDN, j = t % HIDN;
        float s = k2b[j];
        #pragma unroll
        for (int i = 0; i < HIDN; ++i) s += h1[k][i] * k2w[i * HIDN + j];
        h2[k][j] = siluf(s);
    }
    __syncthreads();
    for (int k = 0; k < KK; ++k) {
        float s = k3b[t];
        #pragma unroll
        for (int i = 0; i < HIDN; ++i) s += h2[k][i] * k3w[i * CCH + t];
        flatw[k * CCH + t] = s;   // flat kernel_weights (raw-reshape semantics)
    }
    __syncthreads();
    #pragma unroll
    for (int k = 0; k < KK; ++k) {
        // kw[g,k] = flat[g*7+k]; store plane layout [k][g] for coalesced read
        kwp[k * CCH + t] = flatw[t * KK + k];
        bcomb[k * CCH + t]        = b_off[t * KK + k];
        bcomb[NOFF + k * CCH + t] = b_mask[t * KK + k];
    }
    if (t == 0) {
        float sp = log1pf(expf(raw_sigma[0]));
        sp = fminf(fmaxf(sp, 0.05f), 0.5f);
        float sg = fmaxf(sp, 1e-6f);
        float ev[KK]; float ssum = 0.0f;
        for (int k = 0; k < KK; ++k) {
            float gk = -0.5f + (float)k * (1.0f / 6.0f);
            float d = gk / sg;
            ev[k] = expf(-0.5f * d * d);
            ssum += ev[k];
        }
        ssum = fmaxf(ssum, 1e-8f);
        for (int k = 0; k < KK; ++k) env[k] = ev[k] / ssum;
    }
}

// ---------------- prep: x -> bf16; weights [K=256][N] fp32 -> [N][K=256] bf16 (off/mask permuted) ----------------
__global__ __launch_bounds__(256) void prep_kernel(
    const float* __restrict__ x,
    const float* __restrict__ w_in, const float* __restrict__ dw2_w,
    const float* __restrict__ w_out, const float* __restrict__ w_off,
    const float* __restrict__ w_mask,
    __hip_bfloat16* __restrict__ xbf,
    __hip_bfloat16* __restrict__ wtin, __hip_bfloat16* __restrict__ wtdw2,
    __hip_bfloat16* __restrict__ wtout, __hip_bfloat16* __restrict__ wtcomb)
{
    const int task = blockIdx.y;
    const int tid = threadIdx.x;
    if (task == 0) {
        size_t base = ((size_t)blockIdx.x * 256 + tid) * 4;   // grid.x=4096 covers exactly
        float4 v = *(const float4*)&x[base];
        xbf[base + 0] = __float2bfloat16(v.x);
        xbf[base + 1] = __float2bfloat16(v.y);
        xbf[base + 2] = __float2bfloat16(v.z);
        xbf[base + 3] = __float2bfloat16(v.w);
        return;
    }
    const float* src; __hip_bfloat16* dst; int N; int perm = 0;
    switch (task) {
        case 1: src = w_in;  dst = wtin;  N = 256;  break;
        case 2: src = dw2_w; dst = wtdw2; N = 256;  break;
        case 3: src = w_out; dst = wtout; N = 256;  break;
        case 4: src = w_off;  dst = wtcomb;                      N = NOFF; perm = 1; break;
        default: src = w_mask; dst = wtcomb + (size_t)NOFF * 256; N = NOFF; perm = 1; break;
    }
    int ntiles = 4 * (N / 64);
    if (blockIdx.x >= (unsigned)ntiles) return;
    int tk = (blockIdx.x & 3) * 64;
    int tn = (blockIdx.x >> 2) * 64;
    __shared__ __hip_bfloat16 t[64][66];
    #pragma unroll
    for (int i = 0; i < 16; ++i) {
        int e = i * 256 + tid, kk = e >> 6, nn = e & 63;
        t[kk][nn] = __float2bfloat16(src[(size_t)(tk + kk) * N + tn + nn]);
    }
    __syncthreads();
    #pragma unroll
    for (int i = 0; i < 16; ++i) {
        int e = i * 256 + tid, nn = e >> 6, kk = e & 63;
        int c = tn + nn;
        int cp = perm ? ((c % KK) << 8) + (c / KK) : c;   // plane layout [k][g]
        dst[(size_t)cp * 256 + tk + kk] = t[kk][nn];
    }
}

// ---------------- depthwise conv3 + bias + SiLU -> bf16 ----------------
__global__ __launch_bounds__(256) void dwconv_silu_kernel(
    const float* __restrict__ x, const float* __restrict__ w1,
    const float* __restrict__ b1, __hip_bfloat16* __restrict__ h)
{
    size_t idx = (size_t)blockIdx.x * 256 + threadIdx.x;   // over B*L*C
    int c = (int)(idx & (CCH - 1));
    int l = (int)((idx >> 8) & (LL - 1));
    float s = x[idx] * w1[c * 3 + 1];
    if (l > 0)      s += x[idx - CCH] * w1[c * 3 + 0];
    if (l < LL - 1) s += x[idx + CCH] * w1[c * 3 + 2];
    s += b1[c];
    h[idx] = __float2bfloat16(siluf(s));
}

// ---------------- bf16 MFMA GEMM: C[rows][N] = A[rows][256] @ Bt[N][256]^T + bias ----------------
template<int OUTBF>
__global__ __launch_bounds__(256) void gemm_bf16_k256(
    const __hip_bfloat16* __restrict__ A,
    const __hip_bfloat16* __restrict__ Bt,
    const float* __restrict__ bias,
    void* __restrict__ C, int N)
{
    __shared__ __align__(16) char lds[32768];
    char* As = lds;
    char* Bs = lds + 16384;
    const int tid = threadIdx.x, lane = tid & 63, w = tid >> 6;
    const int wr = w >> 1, wc = w & 1;
    const size_t m0 = (size_t)blockIdx.y * 128, n0 = (size_t)blockIdx.x * 128;

    const int srow = w * 32 + (lane >> 3);
    const int sgr  = (lane & 7) ^ ((lane >> 3) & 7);        // swizzled source granule
    const __hip_bfloat16* a_src = A  + (m0 + srow) * 256 + sgr * 8;
    const __hip_bfloat16* b_src = Bt + (n0 + srow) * 256 + sgr * 8;
    char* a_dst = As + (w * 32) * 128;
    char* b_dst = Bs + (w * 32) * 128;

    f32x4 acc[4][4] = {};

    for (int kt = 0; kt < 4; ++kt) {
        const int k0 = kt * 64;
        #pragma unroll
        for (int inst = 0; inst < 4; ++inst) {
            __builtin_amdgcn_global_load_lds((gvoid_t*)(a_src + k0 + (size_t)inst * 8 * 256),
                                             (svoid_t*)(a_dst + inst * 1024), 16, 0, 0);
            __builtin_amdgcn_global_load_lds((gvoid_t*)(b_src + k0 + (size_t)inst * 8 * 256),
                                             (svoid_t*)(b_dst + inst * 1024), 16, 0, 0);
        }
        __syncthreads();
        #pragma unroll
        for (int ks = 0; ks < 2; ++ks) {
            short8 a[4], b[4];
            #pragma unroll
            for (int i = 0; i < 4; ++i) {
                int mr = wr * 64 + i * 16 + (lane & 15);
                int gk = ks * 4 + (lane >> 4);
                a[i] = *(const short8*)(As + mr * 128 + ((gk ^ (mr & 7)) << 4));
                int nr = wc * 64 + i * 16 + (lane & 15);
                b[i] = *(const short8*)(Bs + nr * 128 + ((gk ^ (nr & 7)) << 4));
            }
            #pragma unroll
            for (int i = 0; i < 4; ++i)
                #pragma unroll
                for (int j = 0; j < 4; ++j)
                    acc[i][j] = __builtin_amdgcn_mfma_f32_16x16x32_bf16(a[i], b[j], acc[i][j], 0, 0, 0);
        }
        __syncthreads();
    }
    #pragma unroll
    for (int j = 0; j < 4; ++j) {
        int col = (int)n0 + wc * 64 + j * 16 + (lane & 15);
        float bb = bias[col];
        #pragma unroll
        for (int i = 0; i < 4; ++i) {
            size_t row0 = m0 + wr * 64 + i * 16 + ((lane >> 4) << 2);
            f32x4 v = acc[i][j];
            #pragma unroll
            for (int q = 0; q < 4; ++q) {
                float val = v[q] + bb;
                if (OUTBF) ((__hip_bfloat16*)C)[(row0 + q) * N + col] = __float2bfloat16(val);
                else       ((float*)C)[(row0 + q) * N + col] = val;
            }
        }
    }
}

// ---------------- sampling + softmax + weighted sum + reductions (8 rows/block) ----------------
__global__ __launch_bounds__(256) void sample_kernel(
    const __hip_bfloat16* __restrict__ xproj,
    const __hip_bfloat16* __restrict__ om,       // [rows][3584] plane layout
    const float* __restrict__ kwp, const float* __restrict__ env,
    __hip_bfloat16* __restrict__ out_pre, float* __restrict__ accum, int chunk_start)
{
    __shared__ __hip_bfloat16 Xs[(ROWS + 10) * CCH];   // 18 rows * 512B = 9216B
    __shared__ float red[256];
    const int r0loc = blockIdx.x * ROWS;
    const int R0 = chunk_start + r0loc;
    const int b = R0 >> 12;
    const int l0 = R0 & (LL - 1);
    const int g = threadIdx.x;

    // stage xproj rows [l0-5, l0+ROWS+4], edge-clamped (handles clip automatically)
    const __hip_bfloat16* xbase = xproj + (size_t)b * LL * CCH;
    {
        int j = g >> 5, c8 = (g & 31) * 8;
        #pragma unroll
        for (int rnd = 0; rnd < 3; ++rnd) {
            int jj = j + rnd * 8;
            if (jj < ROWS + 10) {
                int rr = min(max(l0 - 5 + jj, 0), LL - 1);
                *(short8*)&Xs[jj * CCH + c8] = *(const short8*)&xbase[(size_t)rr * CCH + c8];
            }
        }
    }
    __syncthreads();

    float envr[KK], kwr[KK];
    #pragma unroll
    for (int k = 0; k < KK; ++k) { envr[k] = env[k]; kwr[k] = kwp[k * CCH + g]; }

    float reg_acc = 0.0f, ent_acc = 0.0f;
    for (int rr = 0; rr < ROWS; ++rr) {
        const int l = l0 + rr;
        const __hip_bfloat16* omr = om + (size_t)(r0loc + rr) * NCOMB;
        float mv[KK], sampk[KK];
        #pragma unroll
        for (int k = 0; k < KK; ++k) {
            float ox = __bfloat162float(omr[k * CCH + g]);
            ox = fminf(fmaxf(ox, -15.0f), 15.0f);
            float e2 = __expf(-2.0f * ox);
            float ov = 2.0f * (1.0f - e2) / (1.0f + e2);   // 2*tanh(ox)
            reg_acc += ov * ov;
            float p = (float)(l + k - 3) + ov;
            p = fminf(fmaxf(p, 0.0f), (float)(LL - 1));
            int pf = (int)p;
            float wcf = p - (float)pf;
            int idx  = pf - (l0 - 5);
            int idxc = min(pf + 1, LL - 1) - (l0 - 5);
            float sv = __bfloat162float(Xs[idx * CCH + g]) * (1.0f - wcf)
                     + __bfloat162float(Xs[idxc * CCH + g]) * wcf;
            sampk[k] = sv * kwr[k];
            mv[k] = __bfloat162float(omr[NOFF + k * CCH + g]) * envr[k];
        }
        float mx = mv[0];
        #pragma unroll
        for (int k = 1; k < KK; ++k) mx = fmaxf(mx, mv[k]);
        float e[KK], es = 0.0f;
        #pragma unroll
        for (int k = 0; k < KK; ++k) { e[k] = __expf(mv[k] - mx); es += e[k]; }
        float inv = 1.0f / es;
        float o = 0.0f;
        #pragma unroll
        for (int k = 0; k < KK; ++k) {
            float a = e[k] * inv;
            o += sampk[k] * a;
            ent_acc += a * __logf(a + 1e-8f);
        }
        out_pre[(size_t)(R0 + rr) * CCH + g] = __float2bfloat16(o);
    }

    red[g] = reg_acc;
    __syncthreads();
    for (int s = 128; s > 0; s >>= 1) { if (g < s) red[g] += red[g + s]; __syncthreads(); }
    if (g == 0) atomicAdd(&accum[0], red[0]);
    __syncthreads();
    red[g] = ent_acc;
    __syncthreads();
    for (int s = 128; s > 0; s >>= 1) { if (g < s) red[g] += red[g + s]; __syncthreads(); }
    if (g == 0) atomicAdd(&accum[1], red[0]);
}

// ---------------- finalize scalars ----------------
__global__ void finalize_kernel(const float* __restrict__ accum, float* __restrict__ out_tail)
{
    if (threadIdx.x == 0) {
        out_tail[0] = accum[0] / 29360128.0f;   // B*L*G*K
        out_tail[1] = accum[1] / 4194304.0f;    // B*L*G
    }
}

extern "C" void kernel_launch(void* const* d_in, const int* in_sizes, int n_in,
                              void* d_out, int out_size, void* d_ws, size_t ws_size,
                              hipStream_t stream)
{
    const float* x         = (const float*)d_in[0];
    const float* raw_sigma = (const float*)d_in[1];
    const float* w_in      = (const float*)d_in[2];
    const float* b_in      = (const float*)d_in[3];
    const float* w_out     = (const float*)d_in[4];
    const float* b_out     = (const float*)d_in[5];
    const float* dw1_w     = (const float*)d_in[6];
    const float* dw1_b     = (const float*)d_in[7];
    const float* dw2_w     = (const float*)d_in[8];
    const float* dw2_b     = (const float*)d_in[9];
    const float* w_off     = (const float*)d_in[10];
    const float* b_off     = (const float*)d_in[11];
    const float* w_mask    = (const float*)d_in[12];
    const float* b_mask    = (const float*)d_in[13];
    const float* k0w       = (const float*)d_in[14];
    const float* k0b       = (const float*)d_in[15];
    const float* k1w       = (const float*)d_in[16];
    const float* k1b       = (const float*)d_in[17];
    const float* k2w       = (const float*)d_in[18];
    const float* k2b       = (const float*)d_in[19];
    const float* k3w       = (const float*)d_in[20];
    const float* k3b       = (const float*)d_in[21];

    char* ws = (char*)d_ws;
    const size_t MB8 = (size_t)8 * 1024 * 1024;
    __hip_bfloat16* xbf    = (__hip_bfloat16*)(ws + 0);
    __hip_bfloat16* hbf    = (__hip_bfloat16*)(ws + MB8);        // h, reused as out_pre
    __hip_bfloat16* xdwbf  = (__hip_bfloat16*)(ws + 2 * MB8);
    __hip_bfloat16* xprojb = (__hip_bfloat16*)(ws + 3 * MB8);
    char* wbase = ws + 4 * MB8;
    __hip_bfloat16* wtin   = (__hip_bfloat16*)(wbase);                    // 128KB
    __hip_bfloat16* wtdw2  = (__hip_bfloat16*)(wbase + 131072);           // 128KB
    __hip_bfloat16* wtout  = (__hip_bfloat16*)(wbase + 262144);           // 128KB
    __hip_bfloat16* wtcomb = (__hip_bfloat16*)(wbase + 393216);           // 3584*256*2 = 1792KB
    float* bcomb = (float*)(wbase + 393216 + 1835008);                    // 3584*4
    float* kwp   = bcomb + NCOMB;                                         // 1792*4
    float* env   = kwp + NOFF;
    float* accum = env + 16;
    const size_t fixed = 4 * MB8 + 2265088;   // wbase region rounded up

    // adaptive chunking of combined off|mask bf16 intermediate
    int CH = MTOT;   // 16384
    while (CH > 128) {
        size_t need = fixed + (size_t)CH * NCOMB * 2;
        if (need <= ws_size) break;
        CH >>= 1;
    }
    __hip_bfloat16* omc = (__hip_bfloat16*)(ws + fixed);

    // 1) env / kernel weights (permuted) / permuted biases / zero accumulators
    precompute_kernel<<<1, 256, 0, stream>>>(raw_sigma, k0w, k0b, k1w, k1b,
                                             k2w, k2b, k3w, k3b, b_off, b_mask,
                                             kwp, bcomb, env, accum);
    // 2) conversions + weight transposes (off/mask columns permuted to plane layout)
    prep_kernel<<<dim3(4096, 6), 256, 0, stream>>>(x, w_in, dw2_w, w_out, w_off, w_mask,
                                                   xbf, wtin, wtdw2, wtout, wtcomb);
    // 3) h = silu(dwconv3(x) + dw1_b)  (bf16)
    dwconv_silu_kernel<<<(MTOT * CCH) / 256, 256, 0, stream>>>(x, dw1_w, dw1_b, hbf);
    // 4) x_proj = x @ w_in + b_in   (bf16 out)
    gemm_bf16_k256<1><<<dim3(2, 128), 256, 0, stream>>>(xbf, wtin, b_in, xprojb, 256);
    // 5) x_dw = h @ dw2_w + dw2_b   (bf16 out)
    gemm_bf16_k256<1><<<dim3(2, 128), 256, 0, stream>>>(hbf, wtdw2, dw2_b, xdwbf, 256);
    // 6) chunked: combined off|mask GEMM, fused sampling (out_pre -> hbf)
    for (int c0 = 0; c0 < MTOT; c0 += CH) {
        gemm_bf16_k256<1><<<dim3(NCOMB / 128, CH / 128), 256, 0, stream>>>(
            xdwbf + (size_t)c0 * 256, wtcomb, bcomb, omc, NCOMB);
        sample_kernel<<<CH / ROWS, 256, 0, stream>>>(xprojb, omc, kwp, env, hbf, accum, c0);
    }
    // 7) out = out_pre @ w_out + b_out  (fp32 out)
    gemm_bf16_k256<0><<<dim3(2, 128), 256, 0, stream>>>(hbf, wtout, b_out, (float*)d_out, 256);
    // 8) scalars
    finalize_kernel<<<1, 64, 0, stream>>>(accum, (float*)d_out + (size_t)MTOT * CCH);
}

// Round 4
// 177.853 us; speedup vs baseline: 6.0398x; 1.1310x over previous
//
#include <hip/hip_runtime.h>
#include <hip/hip_bf16.h>
#include <hip/hip_fp16.h>
#include <math.h>

#define BB   4
#define LL   4096
#define CCH  256
#define KK   7
#define HIDN 32
#define MTOT (BB * LL)          // 16384 rows
#define NOFF (CCH * KK)         // 1792
#define NCOMB (2 * NOFF)        // 3584 (off planes | mask planes)
#define ROWS 8                  // rows per sample block

typedef __attribute__((ext_vector_type(8))) short short8;
typedef __attribute__((ext_vector_type(4))) short short4v;
typedef __attribute__((ext_vector_type(4))) float f32x4;
typedef __attribute__((address_space(1))) void gvoid_t;
typedef __attribute__((address_space(3))) void svoid_t;

__device__ __forceinline__ float siluf(float v) { return v / (1.0f + expf(-v)); }

// ---------------- precompute: env, kernel-net MLP (permuted), biases, accumulators ----------------
__global__ __launch_bounds__(256) void precompute_kernel(
    const float* __restrict__ raw_sigma,
    const float* __restrict__ k0w, const float* __restrict__ k0b,
    const float* __restrict__ k1w, const float* __restrict__ k1b,
    const float* __restrict__ k2w, const float* __restrict__ k2b,
    const float* __restrict__ k3w, const float* __restrict__ k3b,
    const float* __restrict__ b_off, const float* __restrict__ b_mask,
    float* __restrict__ kwp, float* __restrict__ bcomb,
    float* __restrict__ env, float* __restrict__ accum)
{
    __shared__ float h0[KK][HIDN];
    __shared__ float h1[KK][HIDN];
    __shared__ float h2[KK][HIDN];
    __shared__ float flatw[NOFF];
    int t = threadIdx.x;
    if (t < 2) accum[t] = 0.0f;
    if (t < KK * HIDN) {
        int k = t / HIDN, j = t % HIDN;
        float gk = -0.5f + (float)k * (1.0f / 6.0f);
        float v = gk * 30.0f * k0w[j] + k0b[j];
        h0[k][j] = siluf(v);
    }
    __syncthreads();
    if (t < KK * HIDN) {
        int k = t / HIDN, j = t % HIDN;
        float s = k1b[j];
        #pragma unroll
        for (int i = 0; i < HIDN; ++i) s += h0[k][i] * k1w[i * HIDN + j];
        h1[k][j] = siluf(s);
    }
    __syncthreads();
    if (t < KK * HIDN) {
        int k = t / HIDN, j = t % HIDN;
        float s = k2b[j];
        #pragma unroll
        for (int i = 0; i < HIDN; ++i) s += h1[k][i] * k2w[i * HIDN + j];
        h2[k][j] = siluf(s);
    }
    __syncthreads();
    for (int k = 0; k < KK; ++k) {
        float s = k3b[t];
        #pragma unroll
        for (int i = 0; i < HIDN; ++i) s += h2[k][i] * k3w[i * CCH + t];
        flatw[k * CCH + t] = s;   // flat kernel_weights (raw-reshape semantics)
    }
    __syncthreads();
    // env first (thread 0), then broadcast via LDS
    __shared__ float envs[KK];
    if (t == 0) {
        float sp = log1pf(expf(raw_sigma[0]));
        sp = fminf(fmaxf(sp, 0.05f), 0.5f);
        float sg = fmaxf(sp, 1e-6f);
        float ev[KK]; float ssum = 0.0f;
        for (int k = 0; k < KK; ++k) {
            float gk = -0.5f + (float)k * (1.0f / 6.0f);
            float d = gk / sg;
            ev[k] = expf(-0.5f * d * d);
            ssum += ev[k];
        }
        ssum = fmaxf(ssum, 1e-8f);
        for (int k = 0; k < KK; ++k) { env[k] = ev[k] / ssum; envs[k] = ev[k] / ssum; }
    }
    __syncthreads();
    #pragma unroll
    for (int k = 0; k < KK; ++k) {
        // kw[g,k] = flat[g*7+k]; store plane layout [k][g] for coalesced read
        kwp[k * CCH + t] = flatw[t * KK + k];
        bcomb[k * CCH + t]        = b_off[t * KK + k];
        bcomb[NOFF + k * CCH + t] = b_mask[t * KK + k];
    }
}

// ---------------- prep: weights [K=256][N] fp32 -> [N][K=256] bf16 (off/mask permuted) ----------------
__global__ __launch_bounds__(256) void prep_kernel(
    const float* __restrict__ w_in, const float* __restrict__ dw2_w,
    const float* __restrict__ w_out, const float* __restrict__ w_off,
    const float* __restrict__ w_mask,
    __hip_bfloat16* __restrict__ wtin, __hip_bfloat16* __restrict__ wtdw2,
    __hip_bfloat16* __restrict__ wtout, __hip_bfloat16* __restrict__ wtcomb)
{
    const int task = blockIdx.y;
    const int tid = threadIdx.x;
    const float* src; __hip_bfloat16* dst; int N; int perm = 0;
    switch (task) {
        case 0: src = w_in;  dst = wtin;  N = 256;  break;
        case 1: src = dw2_w; dst = wtdw2; N = 256;  break;
        case 2: src = w_out; dst = wtout; N = 256;  break;
        case 3: src = w_off;  dst = wtcomb;                       N = NOFF; perm = 1; break;
        default: src = w_mask; dst = wtcomb + (size_t)NOFF * 256; N = NOFF; perm = 1; break;
    }
    int ntiles = 4 * (N / 64);
    if (blockIdx.x >= (unsigned)ntiles) return;
    int tk = (blockIdx.x & 3) * 64;
    int tn = (blockIdx.x >> 2) * 64;
    __shared__ __hip_bfloat16 t[64][66];
    #pragma unroll
    for (int i = 0; i < 16; ++i) {
        int e = i * 256 + tid, kk = e >> 6, nn = e & 63;
        t[kk][nn] = __float2bfloat16(src[(size_t)(tk + kk) * N + tn + nn]);
    }
    __syncthreads();
    #pragma unroll
    for (int i = 0; i < 16; ++i) {
        int e = i * 256 + tid, nn = e >> 6, kk = e & 63;
        int c = tn + nn;
        int cp = perm ? ((c % KK) << 8) + (c / KK) : c;   // plane layout [k][g]
        dst[(size_t)cp * 256 + tk + kk] = t[kk][nn];
    }
}

// ---------------- fused: x -> bf16 copy AND depthwise conv3 + bias + SiLU -> bf16 ----------------
__global__ __launch_bounds__(256) void dwconv_conv_kernel(
    const float* __restrict__ x, const float* __restrict__ w1,
    const float* __restrict__ b1, __hip_bfloat16* __restrict__ xbf,
    __hip_bfloat16* __restrict__ h)
{
    size_t base = ((size_t)blockIdx.x * 256 + threadIdx.x) * 4;   // over B*L*C, 4 ch/thread
    int c = (int)(base & (CCH - 1));
    int l = (int)((base >> 8) & (LL - 1));
    float4 xm = *(const float4*)&x[base];
    float4 xl = make_float4(0.f, 0.f, 0.f, 0.f);
    float4 xr = make_float4(0.f, 0.f, 0.f, 0.f);
    if (l > 0)      xl = *(const float4*)&x[base - CCH];
    if (l < LL - 1) xr = *(const float4*)&x[base + CCH];
    float vm[4] = {xm.x, xm.y, xm.z, xm.w};
    float vl[4] = {xl.x, xl.y, xl.z, xl.w};
    float vr[4] = {xr.x, xr.y, xr.z, xr.w};
    ushort xo[4], ho[4];
    #pragma unroll
    for (int j = 0; j < 4; ++j) {
        int cc = c + j;
        float s = vm[j] * w1[cc * 3 + 1] + vl[j] * w1[cc * 3 + 0] + vr[j] * w1[cc * 3 + 2] + b1[cc];
        __hip_bfloat16 hb = __float2bfloat16(siluf(s));
        __hip_bfloat16 xb = __float2bfloat16(vm[j]);
        ho[j] = *(ushort*)&hb;
        xo[j] = *(ushort*)&xb;
    }
    *(short4v*)&xbf[base] = *(short4v*)xo;
    *(short4v*)&h[base]   = *(short4v*)ho;
}

// ---------------- bf16 MFMA GEMM: C[rows][N] = A[rows][256] @ Bt[N][256]^T + bias ----------------
// MODE 0: f32 out; MODE 1: bf16 out; MODE 2: om epilogue (tanh->fp16 off-planes + reg
// reduction, env-scaled bf16 mask-planes).
template<int MODE>
__global__ __launch_bounds__(256) void gemm_bf16_k256(
    const __hip_bfloat16* __restrict__ A,
    const __hip_bfloat16* __restrict__ Bt,
    const float* __restrict__ bias,
    void* __restrict__ C, int N,
    const float* __restrict__ env, float* __restrict__ accum)
{
    __shared__ __align__(16) char lds[32768];
    char* As = lds;
    char* Bs = lds + 16384;
    const int tid = threadIdx.x, lane = tid & 63, w = tid >> 6;
    const int wr = w >> 1, wc = w & 1;
    const size_t m0 = (size_t)blockIdx.y * 128, n0 = (size_t)blockIdx.x * 128;

    const int srow = w * 32 + (lane >> 3);
    const int sgr  = (lane & 7) ^ ((lane >> 3) & 7);        // swizzled source granule
    const __hip_bfloat16* a_src = A  + (m0 + srow) * 256 + sgr * 8;
    const __hip_bfloat16* b_src = Bt + (n0 + srow) * 256 + sgr * 8;
    char* a_dst = As + (w * 32) * 128;
    char* b_dst = Bs + (w * 32) * 128;

    f32x4 acc[4][4] = {};

    for (int kt = 0; kt < 4; ++kt) {
        const int k0 = kt * 64;
        #pragma unroll
        for (int inst = 0; inst < 4; ++inst) {
            __builtin_amdgcn_global_load_lds((gvoid_t*)(a_src + k0 + (size_t)inst * 8 * 256),
                                             (svoid_t*)(a_dst + inst * 1024), 16, 0, 0);
            __builtin_amdgcn_global_load_lds((gvoid_t*)(b_src + k0 + (size_t)inst * 8 * 256),
                                             (svoid_t*)(b_dst + inst * 1024), 16, 0, 0);
        }
        __syncthreads();
        #pragma unroll
        for (int ks = 0; ks < 2; ++ks) {
            short8 a[4], b[4];
            #pragma unroll
            for (int i = 0; i < 4; ++i) {
                int mr = wr * 64 + i * 16 + (lane & 15);
                int gk = ks * 4 + (lane >> 4);
                a[i] = *(const short8*)(As + mr * 128 + ((gk ^ (mr & 7)) << 4));
                int nr = wc * 64 + i * 16 + (lane & 15);
                b[i] = *(const short8*)(Bs + nr * 128 + ((gk ^ (nr & 7)) << 4));
            }
            #pragma unroll
            for (int i = 0; i < 4; ++i)
                #pragma unroll
                for (int j = 0; j < 4; ++j)
                    acc[i][j] = __builtin_amdgcn_mfma_f32_16x16x32_bf16(a[i], b[j], acc[i][j], 0, 0, 0);
        }
        __syncthreads();
    }
    // epilogue: C/D layout col=lane&15, row=(lane>>4)*4+q  [measured m89/m91]
    const bool is_off = (MODE == 2) && ((int)n0 < NOFF);
    const float envk = (MODE == 2 && !is_off) ? env[((int)n0 - NOFF) >> 8] : 0.0f;
    float reg_acc = 0.0f;
    #pragma unroll
    for (int j = 0; j < 4; ++j) {
        int col = (int)n0 + wc * 64 + j * 16 + (lane & 15);
        float bb = bias[col];
        #pragma unroll
        for (int i = 0; i < 4; ++i) {
            size_t row0 = m0 + wr * 64 + i * 16 + ((lane >> 4) << 2);
            f32x4 v = acc[i][j];
            #pragma unroll
            for (int q = 0; q < 4; ++q) {
                float val = v[q] + bb;
                if (MODE == 0) {
                    ((float*)C)[(row0 + q) * N + col] = val;
                } else if (MODE == 1) {
                    ((__hip_bfloat16*)C)[(row0 + q) * N + col] = __float2bfloat16(val);
                } else {
                    if (is_off) {
                        float xv = fminf(fmaxf(val, -15.0f), 15.0f);
                        float e2 = __expf(-2.0f * xv);
                        float ov = 2.0f * (1.0f - e2) / (1.0f + e2);   // 2*tanh
                        reg_acc += ov * ov;
                        ((__half*)C)[(row0 + q) * N + col] = __float2half(ov);
                    } else {
                        ((__hip_bfloat16*)C)[(row0 + q) * N + col] = __float2bfloat16(val * envk);
                    }
                }
            }
        }
    }
    if (MODE == 2 && is_off) {
        float* red = (float*)lds;
        red[tid] = reg_acc;
        __syncthreads();
        for (int s = 128; s > 0; s >>= 1) { if (tid < s) red[tid] += red[tid + s]; __syncthreads(); }
        if (tid == 0) atomicAdd(&accum[0], red[0]);
    }
}

// ---------------- sampling + softmax + weighted sum + entropy (8 rows/block) ----------------
__global__ __launch_bounds__(256) void sample_kernel(
    const __hip_bfloat16* __restrict__ xproj,
    const ushort* __restrict__ om,       // [rows][3584]: off planes fp16 (=2tanh), mask planes bf16*env
    const float* __restrict__ kwp,
    __hip_bfloat16* __restrict__ out_pre, float* __restrict__ accum, int chunk_start)
{
    __shared__ __hip_bfloat16 Xs[(ROWS + 10) * CCH];   // 18 rows * 512B = 9216B
    __shared__ float red[256];
    const int r0loc = blockIdx.x * ROWS;
    const int R0 = chunk_start + r0loc;
    const int b = R0 >> 12;
    const int l0 = R0 & (LL - 1);
    const int g = threadIdx.x;

    // stage xproj rows [l0-5, l0+ROWS+4], edge-clamped (handles clip automatically)
    const __hip_bfloat16* xbase = xproj + (size_t)b * LL * CCH;
    {
        int j = g >> 5, c8 = (g & 31) * 8;
        #pragma unroll
        for (int rnd = 0; rnd < 3; ++rnd) {
            int jj = j + rnd * 8;
            if (jj < ROWS + 10) {
                int rr = min(max(l0 - 5 + jj, 0), LL - 1);
                *(short8*)&Xs[jj * CCH + c8] = *(const short8*)&xbase[(size_t)rr * CCH + c8];
            }
        }
    }
    __syncthreads();

    float kwr[KK];
    #pragma unroll
    for (int k = 0; k < KK; ++k) kwr[k] = kwp[k * CCH + g];

    float ent_acc = 0.0f;
    for (int rr = 0; rr < ROWS; ++rr) {
        const int l = l0 + rr;
        const ushort* omr = om + (size_t)(r0loc + rr) * NCOMB;
        float mv[KK], sampk[KK];
        #pragma unroll
        for (int k = 0; k < KK; ++k) {
            ushort ou = omr[k * CCH + g];
            float ov = __half2float(*(const __half*)&ou);          // = 2*tanh(off)
            float p = (float)(l + k - 3) + ov;
            p = fminf(fmaxf(p, 0.0f), (float)(LL - 1));
            int pf = (int)p;
            float wcf = p - (float)pf;
            int idx  = pf - (l0 - 5);
            int idxc = min(pf + 1, LL - 1) - (l0 - 5);
            float sv = __bfloat162float(Xs[idx * CCH + g]) * (1.0f - wcf)
                     + __bfloat162float(Xs[idxc * CCH + g]) * wcf;
            sampk[k] = sv * kwr[k];
            ushort mu = omr[NOFF + k * CCH + g];
            mv[k] = __bfloat162float(*(const __hip_bfloat16*)&mu); // already *env
        }
        float mx = mv[0];
        #pragma unroll
        for (int k = 1; k < KK; ++k) mx = fmaxf(mx, mv[k]);
        float e[KK], es = 0.0f, tacc = 0.0f;
        #pragma unroll
        for (int k = 0; k < KK; ++k) {
            float d = mv[k] - mx;
            e[k] = __expf(d);
            es += e[k];
            tacc += e[k] * d;
        }
        float inv = 1.0f / es;
        float o = 0.0f;
        #pragma unroll
        for (int k = 0; k < KK; ++k) o += sampk[k] * e[k];
        o *= inv;
        // sum_k a*ln(a) = (sum e_k*(mv-mx))/es - ln(es)
        ent_acc += tacc * inv - __logf(es);
        out_pre[(size_t)(R0 + rr) * CCH + g] = __float2bfloat16(o);
    }

    red[g] = ent_acc;
    __syncthreads();
    for (int s = 128; s > 0; s >>= 1) { if (g < s) red[g] += red[g + s]; __syncthreads(); }
    if (g == 0) atomicAdd(&accum[1], red[0]);
}

// ---------------- finalize scalars ----------------
__global__ void finalize_kernel(const float* __restrict__ accum, float* __restrict__ out_tail)
{
    if (threadIdx.x == 0) {
        out_tail[0] = accum[0] / 29360128.0f;   // B*L*G*K
        out_tail[1] = accum[1] / 4194304.0f;    // B*L*G
    }
}

extern "C" void kernel_launch(void* const* d_in, const int* in_sizes, int n_in,
                              void* d_out, int out_size, void* d_ws, size_t ws_size,
                              hipStream_t stream)
{
    const float* x         = (const float*)d_in[0];
    const float* raw_sigma = (const float*)d_in[1];
    const float* w_in      = (const float*)d_in[2];
    const float* b_in      = (const float*)d_in[3];
    const float* w_out     = (const float*)d_in[4];
    const float* b_out     = (const float*)d_in[5];
    const float* dw1_w     = (const float*)d_in[6];
    const float* dw1_b     = (const float*)d_in[7];
    const float* dw2_w     = (const float*)d_in[8];
    const float* dw2_b     = (const float*)d_in[9];
    const float* w_off     = (const float*)d_in[10];
    const float* b_off     = (const float*)d_in[11];
    const float* w_mask    = (const float*)d_in[12];
    const float* b_mask    = (const float*)d_in[13];
    const float* k0w       = (const float*)d_in[14];
    const float* k0b       = (const float*)d_in[15];
    const float* k1w       = (const float*)d_in[16];
    const float* k1b       = (const float*)d_in[17];
    const float* k2w       = (const float*)d_in[18];
    const float* k2b       = (const float*)d_in[19];
    const float* k3w       = (const float*)d_in[20];
    const float* k3b       = (const float*)d_in[21];

    char* ws = (char*)d_ws;
    const size_t MB8 = (size_t)8 * 1024 * 1024;
    __hip_bfloat16* xbf    = (__hip_bfloat16*)(ws + 0);
    __hip_bfloat16* hbf    = (__hip_bfloat16*)(ws + MB8);        // h, reused as out_pre
    __hip_bfloat16* xdwbf  = (__hip_bfloat16*)(ws + 2 * MB8);
    __hip_bfloat16* xprojb = (__hip_bfloat16*)(ws + 3 * MB8);
    char* wbase = ws + 4 * MB8;
    __hip_bfloat16* wtin   = (__hip_bfloat16*)(wbase);                    // 128KB
    __hip_bfloat16* wtdw2  = (__hip_bfloat16*)(wbase + 131072);           // 128KB
    __hip_bfloat16* wtout  = (__hip_bfloat16*)(wbase + 262144);           // 128KB
    __hip_bfloat16* wtcomb = (__hip_bfloat16*)(wbase + 393216);           // 3584*256*2 = 1792KB
    float* bcomb = (float*)(wbase + 393216 + 1835008);                    // 3584*4
    float* kwp   = bcomb + NCOMB;                                         // 1792*4
    float* env   = kwp + NOFF;
    float* accum = env + 16;
    const size_t fixed = 4 * MB8 + 2265088;   // wbase region rounded up

    // adaptive chunking of combined off|mask intermediate (fp16/bf16, 2B each)
    int CH = MTOT;   // 16384
    while (CH > 128) {
        size_t need = fixed + (size_t)CH * NCOMB * 2;
        if (need <= ws_size) break;
        CH >>= 1;
    }
    ushort* omc = (ushort*)(ws + fixed);

    // 1) env / kernel weights (permuted) / permuted biases / zero accumulators
    precompute_kernel<<<1, 256, 0, stream>>>(raw_sigma, k0w, k0b, k1w, k1b,
                                             k2w, k2b, k3w, k3b, b_off, b_mask,
                                             kwp, bcomb, env, accum);
    // 2) weight transposes (off/mask columns permuted to plane layout)
    prep_kernel<<<dim3(112, 5), 256, 0, stream>>>(w_in, dw2_w, w_out, w_off, w_mask,
                                                  wtin, wtdw2, wtout, wtcomb);
    // 3) fused: xbf = bf16(x); h = silu(dwconv3(x) + dw1_b)
    dwconv_conv_kernel<<<(MTOT * CCH) / 1024, 256, 0, stream>>>(x, dw1_w, dw1_b, xbf, hbf);
    // 4) x_proj = x @ w_in + b_in   (bf16 out)
    gemm_bf16_k256<1><<<dim3(2, 128), 256, 0, stream>>>(xbf, wtin, b_in, xprojb, 256, env, accum);
    // 5) x_dw = h @ dw2_w + dw2_b   (bf16 out)
    gemm_bf16_k256<1><<<dim3(2, 128), 256, 0, stream>>>(hbf, wtdw2, dw2_b, xdwbf, 256, env, accum);
    // 6) chunked: combined off|mask GEMM w/ tanh+env epilogue, fused sampling (out_pre -> hbf)
    for (int c0 = 0; c0 < MTOT; c0 += CH) {
        gemm_bf16_k256<2><<<dim3(NCOMB / 128, CH / 128), 256, 0, stream>>>(
            xdwbf + (size_t)c0 * 256, wtcomb, bcomb, omc, NCOMB, env, accum);
        sample_kernel<<<CH / ROWS, 256, 0, stream>>>(xprojb, omc, kwp, hbf, accum, c0);
    }
    // 7) out = out_pre @ w_out + b_out  (fp32 out)
    gemm_bf16_k256<0><<<dim3(2, 128), 256, 0, stream>>>(hbf, wtout, b_out, (float*)d_out, 256, env, accum);
    // 8) scalars
    finalize_kernel<<<1, 64, 0, stream>>>(accum, (float*)d_out + (size_t)MTOT * CCH);
}